// Round 8
// baseline (542.287 us; speedup 1.0000x reference)
//
#include <hip/hip_runtime.h>
#include <math.h>

#define NB   16
#define TSEQ 16384
#define DD   128
#define HH   256
constexpr float EPS = 1e-5f;

typedef _Float16 h8v __attribute__((ext_vector_type(8)));
typedef _Float16 h4v __attribute__((ext_vector_type(4)));
typedef float    f4v __attribute__((ext_vector_type(4)));

#define MFMA16(a, b, c) __builtin_amdgcn_mfma_f32_16x16x32_f16(a, b, c, 0, 0, 0)

// LDS strides (halves). 136*2=272B rows: 16B-aligned, 68-word stride -> 2-way
// bank alias on b128 reads (free). 72*2=144B for the [d][t] transpose view.
constexpr int SX_S = 136;
constexpr int SW_S = 136;
constexpr int ST_S = 72;

__device__ __forceinline__ void atomicMaxFloat(float* addr, float val) {
    if (val >= 0.0f) atomicMax((int*)addr, __float_as_int(val));
    else             atomicMin((unsigned int*)addr, __float_as_uint(val));
}

// ---------------------------------------------------------------------------
// K0: weights fp32->fp16 (rms_w folded into Wo), init pooled.
// Wh order: 0 Wq, 1 Wk, 2 Wv, 3 fq1, 4 fq2, 5 fk1, 6 fk2, 7 Wo*rms_w
// Grid: 512 x 256 covers 8*DD*DD = 131072.
// ---------------------------------------------------------------------------
__global__ __launch_bounds__(256) void k0_prep(
    const float* __restrict__ Wq, const float* __restrict__ Wk,
    const float* __restrict__ Wv, const float* __restrict__ fq1,
    const float* __restrict__ fq2, const float* __restrict__ fk1,
    const float* __restrict__ fk2, const float* __restrict__ Wo,
    const float* __restrict__ rmsw,
    _Float16* __restrict__ Wh, float* __restrict__ pooled)
{
    const int i = blockIdx.x * 256 + threadIdx.x;
    if (i < 8 * DD * DD) {
        const int mat = i >> 14;
        const int e   = i & (DD * DD - 1);
        const float* srcs[8] = {Wq, Wk, Wv, fq1, fq2, fk1, fk2, Wo};
        float v = srcs[mat][e];
        if (mat == 7) v *= rmsw[e & (DD - 1)];
        Wh[i] = (_Float16)v;
    }
    if (i < NB * DD)      pooled[i] = -INFINITY;
}

// ---------------------------------------------------------------------------
// K1 (R8: 2x2 wave tiling): 512 threads, 8 waves. Wave wv owns m-tiles
// {2*(wv&1)+i} and n-tiles {2*(wv>>1)+j} (i,j in 0..1) -> 4 output tiles.
// Per k0-step: 2 A b128 reads feed 4 MFMA (was 1:1) -> LDS-balanced.
// Weight B-frags (2 n-tiles) in registers, streamed from L2.
// ---------------------------------------------------------------------------
__global__ __launch_bounds__(512, 4) void k1_qkvfm(
    const float* __restrict__ x, const _Float16* __restrict__ Wh,
    const float* __restrict__ bq1, const float* __restrict__ bq2,
    const float* __restrict__ bk1, const float* __restrict__ bk2,
    _Float16* __restrict__ qf, _Float16* __restrict__ kfT,
    _Float16* __restrict__ vT)
{
    __shared__ _Float16 sX[64 * SX_S];      // 17408 B
    __shared__ _Float16 sCT[DD * ST_S];     // 18432 B union: [64][136] / [128][72]

    const int tid = threadIdx.x;
    const int wv = tid >> 6;
    const int ln = tid & 63, lm = ln & 15, lq = ln >> 4;
    const int mg = wv & 1;                  // m-group: tiles 2mg, 2mg+1
    const int ng = wv >> 1;                 // n-group: tiles 2ng, 2ng+1
    const long t0 = (long)blockIdx.x * 64;
    const int b = (int)(t0 >> 14), tin = (int)(t0 & (TSEQ - 1));

    // biases for this wave's 2 n-tiles
    const float vb1q[2] = {bq1[(ng * 2 + 0) * 16 + lm], bq1[(ng * 2 + 1) * 16 + lm]};
    const float vb2q[2] = {bq2[(ng * 2 + 0) * 16 + lm], bq2[(ng * 2 + 1) * 16 + lm]};
    const float vb1k[2] = {bk1[(ng * 2 + 0) * 16 + lm], bk1[(ng * 2 + 1) * 16 + lm]};
    const float vb2k[2] = {bk2[(ng * 2 + 0) * 16 + lm], bk2[(ng * 2 + 1) * 16 + lm]};

    {   // stage x tile -> sX (fp32 -> fp16)
        const int r = tid >> 3, c0 = (tid & 7) * 16;
        const float* src = x + (t0 + r) * DD + c0;
        _Float16* dst = sX + r * SX_S + c0;
#pragma unroll
        for (int i = 0; i < 4; ++i) {
            const float4 v = *(const float4*)(src + i * 4);
            h4v h; h[0] = (_Float16)v.x; h[1] = (_Float16)v.y;
                   h[2] = (_Float16)v.z; h[3] = (_Float16)v.w;
            *(h4v*)(dst + i * 4) = h;
        }
    }

    auto loadW = [&](int mat, h8v* w) {     // w[j*4+k0], j = n-tile in group
        const _Float16* p = Wh + mat * DD * DD;
#pragma unroll
        for (int j = 0; j < 2; ++j)
#pragma unroll
            for (int k0 = 0; k0 < 4; ++k0)
                w[j * 4 + k0] = *(const h8v*)(p + ((ng * 2 + j) * 16 + lm) * DD + k0 * 32 + lq * 8);
    };
    auto gemm = [&](const _Float16* sA, const h8v* w, f4v acc[2][2]) {
#pragma unroll
        for (int k0 = 0; k0 < 4; ++k0) {
            const h8v a0 = *(const h8v*)(sA + ((mg * 2 + 0) * 16 + lm) * SX_S + k0 * 32 + lq * 8);
            const h8v a1 = *(const h8v*)(sA + ((mg * 2 + 1) * 16 + lm) * SX_S + k0 * 32 + lq * 8);
            acc[0][0] = MFMA16(a0, w[0 * 4 + k0], acc[0][0]);
            acc[0][1] = MFMA16(a0, w[1 * 4 + k0], acc[0][1]);
            acc[1][0] = MFMA16(a1, w[0 * 4 + k0], acc[1][0]);
            acc[1][1] = MFMA16(a1, w[1 * 4 + k0], acc[1][1]);
        }
    };
    auto zero22 = [&](f4v a[2][2]) {
#pragma unroll
        for (int i = 0; i < 2; ++i)
#pragma unroll
            for (int j = 0; j < 2; ++j) { a[i][j][0]=0.f; a[i][j][1]=0.f; a[i][j][2]=0.f; a[i][j][3]=0.f; }
    };
    auto cToC = [&](const f4v a[2][2]) {    // C frags -> sCT [t][d]
#pragma unroll
        for (int i = 0; i < 2; ++i)
#pragma unroll
            for (int j = 0; j < 2; ++j)
#pragma unroll
                for (int r = 0; r < 4; ++r)
                    sCT[((mg * 2 + i) * 16 + lq * 4 + r) * SX_S + (ng * 2 + j) * 16 + lm] = (_Float16)a[i][j][r];
    };
    auto cToT = [&](const f4v a[2][2]) {    // C frags -> sCT [d][t]
#pragma unroll
        for (int i = 0; i < 2; ++i)
#pragma unroll
            for (int j = 0; j < 2; ++j) {
                h4v h;
#pragma unroll
                for (int r = 0; r < 4; ++r) h[r] = (_Float16)a[i][j][r];
                *(h4v*)(sCT + ((ng * 2 + j) * 16 + lm) * ST_S + (mg * 2 + i) * 16 + lq * 4) = h;
            }
    };
    auto copyC = [&](_Float16* dst0) {      // [64][128] -> global [t][d]
        const int r = tid >> 3, c0 = (tid & 7) * 16;
        const _Float16* s = sCT + r * SX_S + c0;
        _Float16* d = dst0 + (t0 + r) * DD + c0;
        *(h8v*)(d)     = *(const h8v*)(s);
        *(h8v*)(d + 8) = *(const h8v*)(s + 8);
    };
    auto copyT = [&](_Float16* dst0) {      // [128][64] -> global [d][t]
        const int dd = tid >> 2, c0 = (tid & 3) * 16;
        const _Float16* s = sCT + dd * ST_S + c0;
        _Float16* d = dst0 + ((long)b * DD + dd) * TSEQ + tin + c0;
        *(h8v*)(d)     = *(const h8v*)(s);
        *(h8v*)(d + 8) = *(const h8v*)(s + 8);
    };

    h8v w[8], w2[8];
    f4v a1[2][2], a2[2][2];

    loadW(0, w);
    __syncthreads();                           // B1: sX ready

    // ---------------- Q chain
    loadW(3, w2);
    zero22(a1); gemm(sX, w, a1);               // q
    cToC(a1);
    __syncthreads();                           // B2: sCT = q
    loadW(4, w);
    zero22(a1); gemm(sCT, w2, a1);             // fq1
    loadW(1, w2);
    zero22(a2); gemm(sCT, w, a2);              // fq2
    __syncthreads();                           // B3
#pragma unroll
    for (int i = 0; i < 2; ++i)
#pragma unroll
        for (int j = 0; j < 2; ++j)
#pragma unroll
            for (int r = 0; r < 4; ++r)
                a1[i][j][r] = (a1[i][j][r] + vb1q[j]) * (a2[i][j][r] + vb2q[j]);
    cToC(a1);
    __syncthreads();                           // B4: sCT = qf
    copyC(qf);
    loadW(5, w);
    zero22(a1); gemm(sX, w2, a1);              // k
    __syncthreads();                           // B5
    cToC(a1);
    __syncthreads();                           // B6: sCT = k
    loadW(6, w2);
    zero22(a1); gemm(sCT, w, a1);              // fk1
    loadW(2, w);
    zero22(a2); gemm(sCT, w2, a2);             // fk2
    __syncthreads();                           // B7
#pragma unroll
    for (int i = 0; i < 2; ++i)
#pragma unroll
        for (int j = 0; j < 2; ++j)
#pragma unroll
            for (int r = 0; r < 4; ++r)
                a1[i][j][r] = (a1[i][j][r] + vb1k[j]) * (a2[i][j][r] + vb2k[j]);
    cToT(a1);
    __syncthreads();                           // B8: sCT = kf^T
    copyT(kfT);
    zero22(a1); gemm(sX, w, a1);               // v
    __syncthreads();                           // B9
    cToT(a1);
    __syncthreads();                           // B10: sCT = v^T
    copyT(vT);
}

// ---------------------------------------------------------------------------
// K2 (split-K, NO atomics, unchanged R7): grid (64, NB) = 1024 blocks.
// ---------------------------------------------------------------------------
constexpr int K2_KT = 256;
constexpr int K2_TC = 64;
constexpr int K2_SPLIT = TSEQ / K2_KT;

__global__ __launch_bounds__(256, 4) void k2_kv(const _Float16* __restrict__ kfT,
                                                const _Float16* __restrict__ vT,
                                                float* __restrict__ STf)
{
    __shared__ _Float16 sV[DD * ST_S];
    __shared__ _Float16 sK[DD * ST_S];
    const int tid = threadIdx.x;
    const int wv = tid >> 6, ln = tid & 63, lm = ln & 15, lq = ln >> 4;
    const int b = blockIdx.y;
    const int tbase = blockIdx.x * K2_KT;
    const _Float16* kb = kfT + (long)b * DD * TSEQ;
    const _Float16* vb = vT  + (long)b * DD * TSEQ;
    f4v acc[2][8];
#pragma unroll
    for (int i = 0; i < 2; ++i)
#pragma unroll
        for (int j = 0; j < 8; ++j) { acc[i][j][0]=0.f; acc[i][j][1]=0.f; acc[i][j][2]=0.f; acc[i][j][3]=0.f; }

    for (int tc = 0; tc < K2_KT; tc += K2_TC) {
        const int r = tid >> 1, c0 = (tid & 1) * 32;
        const long g = (long)r * TSEQ + tbase + tc + c0;
#pragma unroll
        for (int i = 0; i < 4; ++i) {
            *(h8v*)(sV + r * ST_S + c0 + i * 8) = *(const h8v*)(vb + g + i * 8);
            *(h8v*)(sK + r * ST_S + c0 + i * 8) = *(const h8v*)(kb + g + i * 8);
        }
        __syncthreads();
#pragma unroll
        for (int k0 = 0; k0 < 2; ++k0) {
            const h8v a0 = *(const h8v*)(sV + ((wv * 2 + 0) * 16 + lm) * ST_S + k0 * 32 + lq * 8);
            const h8v a1 = *(const h8v*)(sV + ((wv * 2 + 1) * 16 + lm) * ST_S + k0 * 32 + lq * 8);
#pragma unroll
            for (int nt = 0; nt < 8; ++nt) {
                const h8v bb = *(const h8v*)(sK + (nt * 16 + lm) * ST_S + k0 * 32 + lq * 8);
                acc[0][nt] = MFMA16(a0, bb, acc[0][nt]);
                acc[1][nt] = MFMA16(a1, bb, acc[1][nt]);
            }
        }
        __syncthreads();
    }
    float* Pb = STf + (long)(b * K2_SPLIT + blockIdx.x) * (DD * DD);
#pragma unroll
    for (int i = 0; i < 2; ++i)
#pragma unroll
        for (int nt = 0; nt < 8; ++nt)
#pragma unroll
            for (int r = 0; r < 4; ++r)
                Pb[((wv * 2 + i) * 16 + lq * 4 + r) * DD + nt * 16 + lm] = acc[i][nt][r];
}

// ---------------------------------------------------------------------------
// K2r: sum the 64 split-K partials per batch -> fp16 S^T. Coalesced.
// ---------------------------------------------------------------------------
__global__ __launch_bounds__(256) void k2r_reduce(const float* __restrict__ STf,
                                                  _Float16* __restrict__ STh)
{
    const int idx = blockIdx.x * 256 + threadIdx.x;
    const int b = idx >> 14, e = idx & (DD * DD - 1);
    const float* p = STf + (long)b * K2_SPLIT * (DD * DD) + e;
    float s0 = 0.f, s1 = 0.f, s2 = 0.f, s3 = 0.f;
#pragma unroll
    for (int j = 0; j < K2_SPLIT; j += 4) {
        s0 += p[(long)(j + 0) * (DD * DD)];
        s1 += p[(long)(j + 1) * (DD * DD)];
        s2 += p[(long)(j + 2) * (DD * DD)];
        s3 += p[(long)(j + 3) * (DD * DD)];
    }
    STh[idx] = (_Float16)((s0 + s1) + (s2 + s3));
}

// ---------------------------------------------------------------------------
// K3 (R8: 2x4 wave tiling): 128-t slabs, 512 threads, 8 waves.
// Wave wv: eg = wv&1 (e/h'-tiles eg*4+a, a=0..3), tg = wv>>1 (t-tiles tg*2+bt).
// Per k0: 4 af + 2 bf b128 reads feed 8 MFMA (was 9 reads : 8 MFMA).
// RMS over e now spans the 2 eg waves per t -> sPart[2][128] LDS combine.
// Wo' prefetched into registers at start (latency hidden under gemm1).
// ---------------------------------------------------------------------------
constexpr int K3_TC = 128;

__global__ __launch_bounds__(512, 4) void k3_ostage(const _Float16* __restrict__ qf,
                                                    const _Float16* __restrict__ STh,
                                                    const _Float16* __restrict__ WoH,
                                                    float* __restrict__ pooled)
{
    __shared__ _Float16 sA[DD * SW_S];      // S^T [e][d], then Wo' [h'][e]
    __shared__ _Float16 sB[K3_TC * SX_S];   // qf [t][d], then o_n [t][e]
    __shared__ float sPart[2][DD];          // RMS partial sums per (eg, t)
    __shared__ float sRed[8][DD];           // maxpool partials
    const int tid = threadIdx.x;
    const int wv = tid >> 6, ln = tid & 63, lm = ln & 15, lq = ln >> 4;
    const int eg = wv & 1;                  // e/h' half
    const int tg = wv >> 1;                 // t quarter
    const long t0 = (long)blockIdx.x * K3_TC;
    const int b = (int)(t0 >> 14);

    // prefetch Wo' into registers (written to sA after gemm1)
    h8v wo[4];
    {
        const int r = tid >> 2, c0 = (tid & 3) * 32;
        const _Float16* src = WoH + r * DD + c0;
        wo[0] = *(const h8v*)(src);
        wo[1] = *(const h8v*)(src + 8);
        wo[2] = *(const h8v*)(src + 16);
        wo[3] = *(const h8v*)(src + 24);
    }
    {   // stage S^T[b]: 128x128; 512 thr x 4 h8v
        const int r = tid >> 2, c0 = (tid & 3) * 32;
        const _Float16* src = STh + (long)b * DD * DD + r * DD + c0;
        _Float16* dst = sA + r * SW_S + c0;
        *(h8v*)(dst)      = *(const h8v*)(src);
        *(h8v*)(dst + 8)  = *(const h8v*)(src + 8);
        *(h8v*)(dst + 16) = *(const h8v*)(src + 16);
        *(h8v*)(dst + 24) = *(const h8v*)(src + 24);
    }
    {   // stage qf slab: 128x128; 4 h8v per thread
        const int r = tid >> 2, c0 = (tid & 3) * 32;
        const _Float16* src = qf + (t0 + r) * DD + c0;
        _Float16* dst = sB + r * SX_S + c0;
        *(h8v*)(dst)      = *(const h8v*)(src);
        *(h8v*)(dst + 8)  = *(const h8v*)(src + 8);
        *(h8v*)(dst + 16) = *(const h8v*)(src + 16);
        *(h8v*)(dst + 24) = *(const h8v*)(src + 24);
    }
    __syncthreads();                        // B1

    // gemm1: o^T[e][t] = S^T @ qf.  acc[bt][a]: t-tile tg*2+bt, e-tile eg*4+a.
    f4v acc[2][4];
#pragma unroll
    for (int i = 0; i < 2; ++i)
#pragma unroll
        for (int j = 0; j < 4; ++j) { acc[i][j][0]=0.f; acc[i][j][1]=0.f; acc[i][j][2]=0.f; acc[i][j][3]=0.f; }
#pragma unroll
    for (int k0 = 0; k0 < 4; ++k0) {
        const h8v bf0 = *(const h8v*)(sB + ((tg * 2 + 0) * 16 + lm) * SX_S + k0 * 32 + lq * 8);
        const h8v bf1 = *(const h8v*)(sB + ((tg * 2 + 1) * 16 + lm) * SX_S + k0 * 32 + lq * 8);
#pragma unroll
        for (int a = 0; a < 4; ++a) {
            const h8v af = *(const h8v*)(sA + ((eg * 4 + a) * 16 + lm) * SW_S + k0 * 32 + lq * 8);
            acc[0][a] = MFMA16(af, bf0, acc[0][a]);
            acc[1][a] = MFMA16(af, bf1, acc[1][a]);
        }
    }
    // RMS partials: lane's col t = (tg*2+bt)*16+lm; rows e = (eg*4+a)*16+lq*4+r
    float ssp[2] = {0.f, 0.f};
#pragma unroll
    for (int bt = 0; bt < 2; ++bt)
#pragma unroll
        for (int a = 0; a < 4; ++a)
#pragma unroll
            for (int r = 0; r < 4; ++r) ssp[bt] += acc[bt][a][r] * acc[bt][a][r];
#pragma unroll
    for (int bt = 0; bt < 2; ++bt) {
        ssp[bt] += __shfl_xor(ssp[bt], 16, 64);
        ssp[bt] += __shfl_xor(ssp[bt], 32, 64);
    }
    if (lq == 0) {
        sPart[eg][tg * 32 + 0 * 16 + lm] = ssp[0];
        sPart[eg][tg * 32 + 1 * 16 + lm] = ssp[1];
    }
    __syncthreads();                        // B2: gemm1 + partials done
    float sc[2];
#pragma unroll
    for (int bt = 0; bt < 2; ++bt) {
        const int t = tg * 32 + bt * 16 + lm;
        sc[bt] = rsqrtf((sPart[0][t] + sPart[1][t]) * (1.0f / DD) + EPS);
    }
    // o_n -> sB [t][e] (own (t,e) tiles exclusively; all qf reads done at B2)
#pragma unroll
    for (int bt = 0; bt < 2; ++bt)
#pragma unroll
        for (int a = 0; a < 4; ++a) {
            h4v h;
#pragma unroll
            for (int r = 0; r < 4; ++r) h[r] = (_Float16)(acc[bt][a][r] * sc[bt]);
            *(h4v*)(sB + ((tg * 2 + bt) * 16 + lm) * SX_S + (eg * 4 + a) * 16 + lq * 4) = h;
        }
    {   // Wo' regs -> sA (sA reads all done at B2)
        const int r = tid >> 2, c0 = (tid & 3) * 32;
        _Float16* dst = sA + r * SW_S + c0;
        *(h8v*)(dst)      = wo[0];
        *(h8v*)(dst + 8)  = wo[1];
        *(h8v*)(dst + 16) = wo[2];
        *(h8v*)(dst + 24) = wo[3];
    }
    __syncthreads();                        // B3

    // gemm2: y^T[h'][t] = Wo' @ o_n.  acc[bt][a]: t-tile tg*2+bt, h'-tile eg*4+a.
#pragma unroll
    for (int i = 0; i < 2; ++i)
#pragma unroll
        for (int j = 0; j < 4; ++j) { acc[i][j][0]=0.f; acc[i][j][1]=0.f; acc[i][j][2]=0.f; acc[i][j][3]=0.f; }
#pragma unroll
    for (int k0 = 0; k0 < 4; ++k0) {
        const h8v bf0 = *(const h8v*)(sB + ((tg * 2 + 0) * 16 + lm) * SX_S + k0 * 32 + lq * 8);
        const h8v bf1 = *(const h8v*)(sB + ((tg * 2 + 1) * 16 + lm) * SX_S + k0 * 32 + lq * 8);
#pragma unroll
        for (int a = 0; a < 4; ++a) {
            const h8v af = *(const h8v*)(sA + ((eg * 4 + a) * 16 + lm) * SW_S + k0 * 32 + lq * 8);
            acc[0][a] = MFMA16(af, bf0, acc[0][a]);
            acc[1][a] = MFMA16(af, bf1, acc[1][a]);
        }
    }
    // maxpool over t: combine bt pair, reduce over 16 n-lanes, stash per wave
#pragma unroll
    for (int a = 0; a < 4; ++a)
#pragma unroll
        for (int r = 0; r < 4; ++r) {
            float m = fmaxf(acc[0][a][r], acc[1][a][r]);
            m = fmaxf(m, __shfl_xor(m, 1, 64));
            m = fmaxf(m, __shfl_xor(m, 2, 64));
            m = fmaxf(m, __shfl_xor(m, 4, 64));
            m = fmaxf(m, __shfl_xor(m, 8, 64));
            if (lm == 0) sRed[wv][(eg * 4 + a) * 16 + lq * 4 + r] = m;
        }
    __syncthreads();                        // B4
    if (tid < DD) {
        const int egc = tid >> 6;           // which eg half wrote column tid
        float m = sRed[0 * 2 + egc][tid];
#pragma unroll
        for (int g = 1; g < 4; ++g) m = fmaxf(m, sRed[g * 2 + egc][tid]);
        atomicMaxFloat(&pooled[b * DD + tid], m);
    }
}

// ---------------------------------------------------------------------------
// K4: out[b,h] = pooled[b] . Wp[h] + bp[h]
// ---------------------------------------------------------------------------
__global__ __launch_bounds__(HH) void k4_final(const float* __restrict__ pooled,
                                               const float* __restrict__ Wp,
                                               const float* __restrict__ bp,
                                               float* __restrict__ out)
{
    const int b = blockIdx.x;
    const int h = threadIdx.x;
    __shared__ float sp[DD];
    if (h < DD) sp[h] = pooled[b * DD + h];
    __syncthreads();
    float acc = bp[h];
#pragma unroll 8
    for (int d = 0; d < DD; ++d) acc = fmaf(sp[d], Wp[(long)h * DD + d], acc);
    out[b * HH + h] = acc;
}

// ---------------------------------------------------------------------------
extern "C" void kernel_launch(void* const* d_in, const int* in_sizes, int n_in,
                              void* d_out, int out_size, void* d_ws, size_t ws_size,
                              hipStream_t stream)
{
    const float* x      = (const float*)d_in[0];
    const float* Wq     = (const float*)d_in[1];
    const float* Wk     = (const float*)d_in[2];
    const float* Wv     = (const float*)d_in[3];
    const float* fmq_w1 = (const float*)d_in[4];
    const float* fmq_b1 = (const float*)d_in[5];
    const float* fmq_w2 = (const float*)d_in[6];
    const float* fmq_b2 = (const float*)d_in[7];
    const float* fmk_w1 = (const float*)d_in[8];
    const float* fmk_b1 = (const float*)d_in[9];
    const float* fmk_w2 = (const float*)d_in[10];
    const float* fmk_b2 = (const float*)d_in[11];
    const float* rms_w  = (const float*)d_in[12];
    const float* Wo     = (const float*)d_in[13];
    const float* Wp     = (const float*)d_in[14];
    const float* bp     = (const float*)d_in[15];
    float* out = (float*)d_out;

    // ws layout: qf | kfT | vT (fp16) | Wh (fp16) | STf (fp32 split-K partials)
    //            | STh (fp16) | pooled (fp32)
    const long nTD = (long)NB * TSEQ * DD;
    _Float16* qf  = (_Float16*)d_ws;
    _Float16* kfT = qf + nTD;
    _Float16* vT  = kfT + nTD;
    _Float16* Wh  = vT + nTD;
    float* STf    = (float*)(Wh + 8 * DD * DD);
    _Float16* STh = (_Float16*)(STf + (long)NB * K2_SPLIT * DD * DD);
    float* pooled = (float*)(STh + NB * DD * DD);

    k0_prep<<<512, 256, 0, stream>>>(Wq, Wk, Wv, fmq_w1, fmq_w2, fmk_w1, fmk_w2,
                                     Wo, rms_w, Wh, pooled);
    k1_qkvfm<<<(NB * TSEQ) / 64, 512, 0, stream>>>(
        x, Wh, fmq_b1, fmq_b2, fmk_b1, fmk_b2, qf, kfT, vT);
    k2_kv<<<dim3(K2_SPLIT, NB), 256, 0, stream>>>(kfT, vT, STf);
    k2r_reduce<<<(NB * DD * DD) / 256, 256, 0, stream>>>(STf, STh);
    k3_ostage<<<(NB * TSEQ) / K3_TC, 512, 0, stream>>>(qf, STh, Wh + 7 * DD * DD, pooled);
    k4_final<<<NB, HH, 0, stream>>>(pooled, Wp, bp, out);
}

// Round 9
// 530.026 us; speedup vs baseline: 1.0231x; 1.0231x over previous
//
#include <hip/hip_runtime.h>
#include <math.h>

#define NB   16
#define TSEQ 16384
#define DD   128
#define HH   256
constexpr float EPS = 1e-5f;

typedef _Float16 h8v __attribute__((ext_vector_type(8)));
typedef _Float16 h4v __attribute__((ext_vector_type(4)));
typedef float    f4v __attribute__((ext_vector_type(4)));

#define MFMA16(a, b, c) __builtin_amdgcn_mfma_f32_16x16x32_f16(a, b, c, 0, 0, 0)

constexpr int SX_S = 136;
constexpr int SW_S = 136;
constexpr int ST_S = 72;

__device__ __forceinline__ void atomicMaxFloat(float* addr, float val) {
    if (val >= 0.0f) atomicMax((int*)addr, __float_as_int(val));
    else             atomicMin((unsigned int*)addr, __float_as_uint(val));
}

// ---------------------------------------------------------------------------
// K0: weights fp32->fp16 (rms_w folded into Wo), init pooled.
// ---------------------------------------------------------------------------
__global__ __launch_bounds__(256) void k0_prep(
    const float* __restrict__ Wq, const float* __restrict__ Wk,
    const float* __restrict__ Wv, const float* __restrict__ fq1,
    const float* __restrict__ fq2, const float* __restrict__ fk1,
    const float* __restrict__ fk2, const float* __restrict__ Wo,
    const float* __restrict__ rmsw,
    _Float16* __restrict__ Wh, float* __restrict__ pooled)
{
    const int i = blockIdx.x * 256 + threadIdx.x;
    if (i < 8 * DD * DD) {
        const int mat = i >> 14;
        const int e   = i & (DD * DD - 1);
        const float* srcs[8] = {Wq, Wk, Wv, fq1, fq2, fk1, fk2, Wo};
        float v = srcs[mat][e];
        if (mat == 7) v *= rmsw[e & (DD - 1)];
        Wh[i] = (_Float16)v;
    }
    if (i < NB * DD)      pooled[i] = -INFINITY;
}

// ---------------------------------------------------------------------------
// K1 (R7 structure, R9: launch_bounds (512,8) -> 4 blocks/CU for barrier
// overlap; VGPR 48 fits the 64-cap). Wave wv owns n-tile wv; weight B-frags
// in registers (w[4]/w2[4] = 32 VGPR), prefetched one gemm ahead.
// ---------------------------------------------------------------------------
__global__ __launch_bounds__(512, 8) void k1_qkvfm(
    const float* __restrict__ x, const _Float16* __restrict__ Wh,
    const float* __restrict__ bq1, const float* __restrict__ bq2,
    const float* __restrict__ bk1, const float* __restrict__ bk2,
    _Float16* __restrict__ qf, _Float16* __restrict__ kfT,
    _Float16* __restrict__ vT)
{
    __shared__ _Float16 sX[64 * SX_S];      // 17408 B
    __shared__ _Float16 sCT[DD * ST_S];     // 18432 B union: [64][136] / [128][72]

    const int tid = threadIdx.x;
    const int wv = tid >> 6;                // 0..7 -> n-tile
    const int ln = tid & 63, lm = ln & 15, lq = ln >> 4;
    const long t0 = (long)blockIdx.x * 64;
    const int b = (int)(t0 >> 14), tin = (int)(t0 & (TSEQ - 1));

    const float vb1q = bq1[wv * 16 + lm], vb2q = bq2[wv * 16 + lm];
    const float vb1k = bk1[wv * 16 + lm], vb2k = bk2[wv * 16 + lm];

    {
        const int r = tid >> 3, c0 = (tid & 7) * 16;
        const float* src = x + (t0 + r) * DD + c0;
        _Float16* dst = sX + r * SX_S + c0;
#pragma unroll
        for (int i = 0; i < 4; ++i) {
            const float4 v = *(const float4*)(src + i * 4);
            h4v h; h[0] = (_Float16)v.x; h[1] = (_Float16)v.y;
                   h[2] = (_Float16)v.z; h[3] = (_Float16)v.w;
            *(h4v*)(dst + i * 4) = h;
        }
    }

    auto loadW = [&](int mat, h8v* w) {
        const _Float16* p = Wh + mat * DD * DD + (wv * 16 + lm) * DD + lq * 8;
#pragma unroll
        for (int k0 = 0; k0 < 4; ++k0) w[k0] = *(const h8v*)(p + k0 * 32);
    };
    auto gemm = [&](const _Float16* sA, const h8v* w, f4v* acc) {
#pragma unroll
        for (int k0 = 0; k0 < 4; ++k0)
#pragma unroll
            for (int mt = 0; mt < 4; ++mt) {
                const h8v a = *(const h8v*)(sA + (mt * 16 + lm) * SX_S + k0 * 32 + lq * 8);
                acc[mt] = MFMA16(a, w[k0], acc[mt]);
            }
    };
    auto zero4 = [&](f4v* a) {
#pragma unroll
        for (int i = 0; i < 4; ++i) { a[i][0] = 0.f; a[i][1] = 0.f; a[i][2] = 0.f; a[i][3] = 0.f; }
    };
    auto cToC = [&](const f4v* a) {
#pragma unroll
        for (int mt = 0; mt < 4; ++mt)
#pragma unroll
            for (int r = 0; r < 4; ++r)
                sCT[(mt * 16 + lq * 4 + r) * SX_S + wv * 16 + lm] = (_Float16)a[mt][r];
    };
    auto cToT = [&](const f4v* a) {
#pragma unroll
        for (int mt = 0; mt < 4; ++mt) {
            h4v h;
#pragma unroll
            for (int r = 0; r < 4; ++r) h[r] = (_Float16)a[mt][r];
            *(h4v*)(sCT + (wv * 16 + lm) * ST_S + mt * 16 + lq * 4) = h;
        }
    };
    auto copyC = [&](_Float16* dst0) {
        const int r = tid >> 3, c0 = (tid & 7) * 16;
        const _Float16* s = sCT + r * SX_S + c0;
        _Float16* d = dst0 + (t0 + r) * DD + c0;
        *(h8v*)(d)     = *(const h8v*)(s);
        *(h8v*)(d + 8) = *(const h8v*)(s + 8);
    };
    auto copyT = [&](_Float16* dst0) {
        const int dd = tid >> 2, c0 = (tid & 3) * 16;
        const _Float16* s = sCT + dd * ST_S + c0;
        _Float16* d = dst0 + ((long)b * DD + dd) * TSEQ + tin + c0;
        *(h8v*)(d)     = *(const h8v*)(s);
        *(h8v*)(d + 8) = *(const h8v*)(s + 8);
    };

    h8v w[4], w2[4];
    f4v a1[4], a2[4];

    loadW(0, w);
    __syncthreads();                           // B1: sX ready

    // ---------------- Q chain
    loadW(3, w2);
    zero4(a1); gemm(sX, w, a1);                // q
    cToC(a1);
    __syncthreads();                           // B2: sCT = q
    loadW(4, w);
    zero4(a1); gemm(sCT, w2, a1);              // fq1
    loadW(1, w2);
    zero4(a2); gemm(sCT, w, a2);               // fq2
    __syncthreads();                           // B3
#pragma unroll
    for (int mt = 0; mt < 4; ++mt)
#pragma unroll
        for (int r = 0; r < 4; ++r)
            a1[mt][r] = (a1[mt][r] + vb1q) * (a2[mt][r] + vb2q);
    cToC(a1);
    __syncthreads();                           // B4: sCT = qf
    copyC(qf);
    loadW(5, w);
    zero4(a1); gemm(sX, w2, a1);               // k
    __syncthreads();                           // B5
    cToC(a1);
    __syncthreads();                           // B6: sCT = k
    loadW(6, w2);
    zero4(a1); gemm(sCT, w, a1);               // fk1
    loadW(2, w);
    zero4(a2); gemm(sCT, w2, a2);              // fk2
    __syncthreads();                           // B7
#pragma unroll
    for (int mt = 0; mt < 4; ++mt)
#pragma unroll
        for (int r = 0; r < 4; ++r)
            a1[mt][r] = (a1[mt][r] + vb1k) * (a2[mt][r] + vb2k);
    cToT(a1);
    __syncthreads();                           // B8: sCT = kf^T
    copyT(kfT);
    zero4(a1); gemm(sX, w, a1);                // v
    __syncthreads();                           // B9
    cToT(a1);
    __syncthreads();                           // B10: sCT = v^T
    copyT(vT);
}

// ---------------------------------------------------------------------------
// K2 (split-K, no atomics, unchanged): grid (64, NB) = 1024 blocks.
// ---------------------------------------------------------------------------
constexpr int K2_KT = 256;
constexpr int K2_TC = 64;
constexpr int K2_SPLIT = TSEQ / K2_KT;

__global__ __launch_bounds__(256, 4) void k2_kv(const _Float16* __restrict__ kfT,
                                                const _Float16* __restrict__ vT,
                                                float* __restrict__ STf)
{
    __shared__ _Float16 sV[DD * ST_S];
    __shared__ _Float16 sK[DD * ST_S];
    const int tid = threadIdx.x;
    const int wv = tid >> 6, ln = tid & 63, lm = ln & 15, lq = ln >> 4;
    const int b = blockIdx.y;
    const int tbase = blockIdx.x * K2_KT;
    const _Float16* kb = kfT + (long)b * DD * TSEQ;
    const _Float16* vb = vT  + (long)b * DD * TSEQ;
    f4v acc[2][8];
#pragma unroll
    for (int i = 0; i < 2; ++i)
#pragma unroll
        for (int j = 0; j < 8; ++j) { acc[i][j][0]=0.f; acc[i][j][1]=0.f; acc[i][j][2]=0.f; acc[i][j][3]=0.f; }

    for (int tc = 0; tc < K2_KT; tc += K2_TC) {
        const int r = tid >> 1, c0 = (tid & 1) * 32;
        const long g = (long)r * TSEQ + tbase + tc + c0;
#pragma unroll
        for (int i = 0; i < 4; ++i) {
            *(h8v*)(sV + r * ST_S + c0 + i * 8) = *(const h8v*)(vb + g + i * 8);
            *(h8v*)(sK + r * ST_S + c0 + i * 8) = *(const h8v*)(kb + g + i * 8);
        }
        __syncthreads();
#pragma unroll
        for (int k0 = 0; k0 < 2; ++k0) {
            const h8v a0 = *(const h8v*)(sV + ((wv * 2 + 0) * 16 + lm) * ST_S + k0 * 32 + lq * 8);
            const h8v a1 = *(const h8v*)(sV + ((wv * 2 + 1) * 16 + lm) * ST_S + k0 * 32 + lq * 8);
#pragma unroll
            for (int nt = 0; nt < 8; ++nt) {
                const h8v bb = *(const h8v*)(sK + (nt * 16 + lm) * ST_S + k0 * 32 + lq * 8);
                acc[0][nt] = MFMA16(a0, bb, acc[0][nt]);
                acc[1][nt] = MFMA16(a1, bb, acc[1][nt]);
            }
        }
        __syncthreads();
    }
    float* Pb = STf + (long)(b * K2_SPLIT + blockIdx.x) * (DD * DD);
#pragma unroll
    for (int i = 0; i < 2; ++i)
#pragma unroll
        for (int nt = 0; nt < 8; ++nt)
#pragma unroll
            for (int r = 0; r < 4; ++r)
                Pb[((wv * 2 + i) * 16 + lq * 4 + r) * DD + nt * 16 + lm] = acc[i][nt][r];
}

// ---------------------------------------------------------------------------
// K2r: sum the 64 split-K partials per batch -> fp16 S^T.
// ---------------------------------------------------------------------------
__global__ __launch_bounds__(256) void k2r_reduce(const float* __restrict__ STf,
                                                  _Float16* __restrict__ STh)
{
    const int idx = blockIdx.x * 256 + threadIdx.x;
    const int b = idx >> 14, e = idx & (DD * DD - 1);
    const float* p = STf + (long)b * K2_SPLIT * (DD * DD) + e;
    float s0 = 0.f, s1 = 0.f, s2 = 0.f, s3 = 0.f;
#pragma unroll
    for (int j = 0; j < K2_SPLIT; j += 4) {
        s0 += p[(long)(j + 0) * (DD * DD)];
        s1 += p[(long)(j + 1) * (DD * DD)];
        s2 += p[(long)(j + 2) * (DD * DD)];
        s3 += p[(long)(j + 3) * (DD * DD)];
    }
    STh[idx] = (_Float16)((s0 + s1) + (s2 + s3));
}

// ---------------------------------------------------------------------------
// K3 (R8 2x4 wave tiling, validated): 128-t slabs, 512 threads, 8 waves.
// ---------------------------------------------------------------------------
constexpr int K3_TC = 128;

__global__ __launch_bounds__(512, 4) void k3_ostage(const _Float16* __restrict__ qf,
                                                    const _Float16* __restrict__ STh,
                                                    const _Float16* __restrict__ WoH,
                                                    float* __restrict__ pooled)
{
    __shared__ _Float16 sA[DD * SW_S];
    __shared__ _Float16 sB[K3_TC * SX_S];
    __shared__ float sPart[2][DD];
    __shared__ float sRed[8][DD];
    const int tid = threadIdx.x;
    const int wv = tid >> 6, ln = tid & 63, lm = ln & 15, lq = ln >> 4;
    const int eg = wv & 1;
    const int tg = wv >> 1;
    const long t0 = (long)blockIdx.x * K3_TC;
    const int b = (int)(t0 >> 14);

    h8v wo[4];
    {
        const int r = tid >> 2, c0 = (tid & 3) * 32;
        const _Float16* src = WoH + r * DD + c0;
        wo[0] = *(const h8v*)(src);
        wo[1] = *(const h8v*)(src + 8);
        wo[2] = *(const h8v*)(src + 16);
        wo[3] = *(const h8v*)(src + 24);
    }
    {
        const int r = tid >> 2, c0 = (tid & 3) * 32;
        const _Float16* src = STh + (long)b * DD * DD + r * DD + c0;
        _Float16* dst = sA + r * SW_S + c0;
        *(h8v*)(dst)      = *(const h8v*)(src);
        *(h8v*)(dst + 8)  = *(const h8v*)(src + 8);
        *(h8v*)(dst + 16) = *(const h8v*)(src + 16);
        *(h8v*)(dst + 24) = *(const h8v*)(src + 24);
    }
    {
        const int r = tid >> 2, c0 = (tid & 3) * 32;
        const _Float16* src = qf + (t0 + r) * DD + c0;
        _Float16* dst = sB + r * SX_S + c0;
        *(h8v*)(dst)      = *(const h8v*)(src);
        *(h8v*)(dst + 8)  = *(const h8v*)(src + 8);
        *(h8v*)(dst + 16) = *(const h8v*)(src + 16);
        *(h8v*)(dst + 24) = *(const h8v*)(src + 24);
    }
    __syncthreads();                        // B1

    f4v acc[2][4];
#pragma unroll
    for (int i = 0; i < 2; ++i)
#pragma unroll
        for (int j = 0; j < 4; ++j) { acc[i][j][0]=0.f; acc[i][j][1]=0.f; acc[i][j][2]=0.f; acc[i][j][3]=0.f; }
#pragma unroll
    for (int k0 = 0; k0 < 4; ++k0) {
        const h8v bf0 = *(const h8v*)(sB + ((tg * 2 + 0) * 16 + lm) * SX_S + k0 * 32 + lq * 8);
        const h8v bf1 = *(const h8v*)(sB + ((tg * 2 + 1) * 16 + lm) * SX_S + k0 * 32 + lq * 8);
#pragma unroll
        for (int a = 0; a < 4; ++a) {
            const h8v af = *(const h8v*)(sA + ((eg * 4 + a) * 16 + lm) * SW_S + k0 * 32 + lq * 8);
            acc[0][a] = MFMA16(af, bf0, acc[0][a]);
            acc[1][a] = MFMA16(af, bf1, acc[1][a]);
        }
    }
    float ssp[2] = {0.f, 0.f};
#pragma unroll
    for (int bt = 0; bt < 2; ++bt)
#pragma unroll
        for (int a = 0; a < 4; ++a)
#pragma unroll
            for (int r = 0; r < 4; ++r) ssp[bt] += acc[bt][a][r] * acc[bt][a][r];
#pragma unroll
    for (int bt = 0; bt < 2; ++bt) {
        ssp[bt] += __shfl_xor(ssp[bt], 16, 64);
        ssp[bt] += __shfl_xor(ssp[bt], 32, 64);
    }
    if (lq == 0) {
        sPart[eg][tg * 32 + 0 * 16 + lm] = ssp[0];
        sPart[eg][tg * 32 + 1 * 16 + lm] = ssp[1];
    }
    __syncthreads();                        // B2
    float sc[2];
#pragma unroll
    for (int bt = 0; bt < 2; ++bt) {
        const int t = tg * 32 + bt * 16 + lm;
        sc[bt] = rsqrtf((sPart[0][t] + sPart[1][t]) * (1.0f / DD) + EPS);
    }
#pragma unroll
    for (int bt = 0; bt < 2; ++bt)
#pragma unroll
        for (int a = 0; a < 4; ++a) {
            h4v h;
#pragma unroll
            for (int r = 0; r < 4; ++r) h[r] = (_Float16)(acc[bt][a][r] * sc[bt]);
            *(h4v*)(sB + ((tg * 2 + bt) * 16 + lm) * SX_S + (eg * 4 + a) * 16 + lq * 4) = h;
        }
    {
        const int r = tid >> 2, c0 = (tid & 3) * 32;
        _Float16* dst = sA + r * SW_S + c0;
        *(h8v*)(dst)      = wo[0];
        *(h8v*)(dst + 8)  = wo[1];
        *(h8v*)(dst + 16) = wo[2];
        *(h8v*)(dst + 24) = wo[3];
    }
    __syncthreads();                        // B3

#pragma unroll
    for (int i = 0; i < 2; ++i)
#pragma unroll
        for (int j = 0; j < 4; ++j) { acc[i][j][0]=0.f; acc[i][j][1]=0.f; acc[i][j][2]=0.f; acc[i][j][3]=0.f; }
#pragma unroll
    for (int k0 = 0; k0 < 4; ++k0) {
        const h8v bf0 = *(const h8v*)(sB + ((tg * 2 + 0) * 16 + lm) * SX_S + k0 * 32 + lq * 8);
        const h8v bf1 = *(const h8v*)(sB + ((tg * 2 + 1) * 16 + lm) * SX_S + k0 * 32 + lq * 8);
#pragma unroll
        for (int a = 0; a < 4; ++a) {
            const h8v af = *(const h8v*)(sA + ((eg * 4 + a) * 16 + lm) * SW_S + k0 * 32 + lq * 8);
            acc[0][a] = MFMA16(af, bf0, acc[0][a]);
            acc[1][a] = MFMA16(af, bf1, acc[1][a]);
        }
    }
#pragma unroll
    for (int a = 0; a < 4; ++a)
#pragma unroll
        for (int r = 0; r < 4; ++r) {
            float m = fmaxf(acc[0][a][r], acc[1][a][r]);
            m = fmaxf(m, __shfl_xor(m, 1, 64));
            m = fmaxf(m, __shfl_xor(m, 2, 64));
            m = fmaxf(m, __shfl_xor(m, 4, 64));
            m = fmaxf(m, __shfl_xor(m, 8, 64));
            if (lm == 0) sRed[wv][(eg * 4 + a) * 16 + lq * 4 + r] = m;
        }
    __syncthreads();                        // B4
    if (tid < DD) {
        const int egc = tid >> 6;
        float m = sRed[0 * 2 + egc][tid];
#pragma unroll
        for (int g = 1; g < 4; ++g) m = fmaxf(m, sRed[g * 2 + egc][tid]);
        atomicMaxFloat(&pooled[b * DD + tid], m);
    }
}

// ---------------------------------------------------------------------------
// K4: out[b,h] = pooled[b] . Wp[h] + bp[h]
// ---------------------------------------------------------------------------
__global__ __launch_bounds__(HH) void k4_final(const float* __restrict__ pooled,
                                               const float* __restrict__ Wp,
                                               const float* __restrict__ bp,
                                               float* __restrict__ out)
{
    const int b = blockIdx.x;
    const int h = threadIdx.x;
    __shared__ float sp[DD];
    if (h < DD) sp[h] = pooled[b * DD + h];
    __syncthreads();
    float acc = bp[h];
#pragma unroll 8
    for (int d = 0; d < DD; ++d) acc = fmaf(sp[d], Wp[(long)h * DD + d], acc);
    out[b * HH + h] = acc;
}

// ---------------------------------------------------------------------------
extern "C" void kernel_launch(void* const* d_in, const int* in_sizes, int n_in,
                              void* d_out, int out_size, void* d_ws, size_t ws_size,
                              hipStream_t stream)
{
    const float* x      = (const float*)d_in[0];
    const float* Wq     = (const float*)d_in[1];
    const float* Wk     = (const float*)d_in[2];
    const float* Wv     = (const float*)d_in[3];
    const float* fmq_w1 = (const float*)d_in[4];
    const float* fmq_b1 = (const float*)d_in[5];
    const float* fmq_w2 = (const float*)d_in[6];
    const float* fmq_b2 = (const float*)d_in[7];
    const float* fmk_w1 = (const float*)d_in[8];
    const float* fmk_b1 = (const float*)d_in[9];
    const float* fmk_w2 = (const float*)d_in[10];
    const float* fmk_b2 = (const float*)d_in[11];
    const float* rms_w  = (const float*)d_in[12];
    const float* Wo     = (const float*)d_in[13];
    const float* Wp     = (const float*)d_in[14];
    const float* bp     = (const float*)d_in[15];
    float* out = (float*)d_out;

    const long nTD = (long)NB * TSEQ * DD;
    _Float16* qf  = (_Float16*)d_ws;
    _Float16* kfT = qf + nTD;
    _Float16* vT  = kfT + nTD;
    _Float16* Wh  = vT + nTD;
    float* STf    = (float*)(Wh + 8 * DD * DD);
    _Float16* STh = (_Float16*)(STf + (long)NB * K2_SPLIT * DD * DD);
    float* pooled = (float*)(STh + NB * DD * DD);

    k0_prep<<<512, 256, 0, stream>>>(Wq, Wk, Wv, fmq_w1, fmq_w2, fmk_w1, fmk_w2,
                                     Wo, rms_w, Wh, pooled);
    k1_qkvfm<<<(NB * TSEQ) / 64, 512, 0, stream>>>(
        x, Wh, fmq_b1, fmq_b2, fmk_b1, fmk_b2, qf, kfT, vT);
    k2_kv<<<dim3(K2_SPLIT, NB), 256, 0, stream>>>(kfT, vT, STf);
    k2r_reduce<<<(NB * DD * DD) / 256, 256, 0, stream>>>(STf, STh);
    k3_ostage<<<(NB * TSEQ) / K3_TC, 512, 0, stream>>>(qf, STh, Wh + 7 * DD * DD, pooled);
    k4_final<<<NB, HH, 0, stream>>>(pooled, Wp, bp, out);
}

// Round 10
// 460.020 us; speedup vs baseline: 1.1788x; 1.1522x over previous
//
#include <hip/hip_runtime.h>
#include <math.h>

#define NB   16
#define TSEQ 16384
#define DD   128
#define HH   256
constexpr float EPS = 1e-5f;

typedef _Float16 h8v __attribute__((ext_vector_type(8)));
typedef _Float16 h4v __attribute__((ext_vector_type(4)));
typedef float    f4v __attribute__((ext_vector_type(4)));

#define MFMA16(a, b, c) __builtin_amdgcn_mfma_f32_16x16x32_f16(a, b, c, 0, 0, 0)

constexpr int SX_S = 136;
constexpr int SW_S = 136;
constexpr int ST_S = 72;

__device__ __forceinline__ void atomicMaxFloat(float* addr, float val) {
    if (val >= 0.0f) atomicMax((int*)addr, __float_as_int(val));
    else             atomicMin((unsigned int*)addr, __float_as_uint(val));
}

// ---------------------------------------------------------------------------
// K0: weights fp32->fp16 (rms_w folded into Wo), init pooled.
// ---------------------------------------------------------------------------
__global__ __launch_bounds__(256) void k0_prep(
    const float* __restrict__ Wq, const float* __restrict__ Wk,
    const float* __restrict__ Wv, const float* __restrict__ fq1,
    const float* __restrict__ fq2, const float* __restrict__ fk1,
    const float* __restrict__ fk2, const float* __restrict__ Wo,
    const float* __restrict__ rmsw,
    _Float16* __restrict__ Wh, float* __restrict__ pooled)
{
    const int i = blockIdx.x * 256 + threadIdx.x;
    if (i < 8 * DD * DD) {
        const int mat = i >> 14;
        const int e   = i & (DD * DD - 1);
        const float* srcs[8] = {Wq, Wk, Wv, fq1, fq2, fk1, fk2, Wo};
        float v = srcs[mat][e];
        if (mat == 7) v *= rmsw[e & (DD - 1)];
        Wh[i] = (_Float16)v;
    }
    if (i < NB * DD)      pooled[i] = -INFINITY;
}

// ---------------------------------------------------------------------------
// K1 (R7 structure; R10: launch_bounds (512,6) -> 3 blocks/CU min-residency,
// VGPR cap ~85 so the 48-VGPR body does NOT spill (R9's (512,8) forced 32
// VGPR -> 326 MB scratch traffic)). Wave wv owns n-tile wv; weight B-frags
// in registers, prefetched one gemm ahead.
// ---------------------------------------------------------------------------
__global__ __launch_bounds__(512, 6) void k1_qkvfm(
    const float* __restrict__ x, const _Float16* __restrict__ Wh,
    const float* __restrict__ bq1, const float* __restrict__ bq2,
    const float* __restrict__ bk1, const float* __restrict__ bk2,
    _Float16* __restrict__ qf, _Float16* __restrict__ kfT,
    _Float16* __restrict__ vT)
{
    __shared__ _Float16 sX[64 * SX_S];      // 17408 B
    __shared__ _Float16 sCT[DD * ST_S];     // 18432 B union: [64][136] / [128][72]

    const int tid = threadIdx.x;
    const int wv = tid >> 6;                // 0..7 -> n-tile
    const int ln = tid & 63, lm = ln & 15, lq = ln >> 4;
    const long t0 = (long)blockIdx.x * 64;
    const int b = (int)(t0 >> 14), tin = (int)(t0 & (TSEQ - 1));

    const float vb1q = bq1[wv * 16 + lm], vb2q = bq2[wv * 16 + lm];
    const float vb1k = bk1[wv * 16 + lm], vb2k = bk2[wv * 16 + lm];

    {
        const int r = tid >> 3, c0 = (tid & 7) * 16;
        const float* src = x + (t0 + r) * DD + c0;
        _Float16* dst = sX + r * SX_S + c0;
#pragma unroll
        for (int i = 0; i < 4; ++i) {
            const float4 v = *(const float4*)(src + i * 4);
            h4v h; h[0] = (_Float16)v.x; h[1] = (_Float16)v.y;
                   h[2] = (_Float16)v.z; h[3] = (_Float16)v.w;
            *(h4v*)(dst + i * 4) = h;
        }
    }

    auto loadW = [&](int mat, h8v* w) {
        const _Float16* p = Wh + mat * DD * DD + (wv * 16 + lm) * DD + lq * 8;
#pragma unroll
        for (int k0 = 0; k0 < 4; ++k0) w[k0] = *(const h8v*)(p + k0 * 32);
    };
    auto gemm = [&](const _Float16* sA, const h8v* w, f4v* acc) {
#pragma unroll
        for (int k0 = 0; k0 < 4; ++k0)
#pragma unroll
            for (int mt = 0; mt < 4; ++mt) {
                const h8v a = *(const h8v*)(sA + (mt * 16 + lm) * SX_S + k0 * 32 + lq * 8);
                acc[mt] = MFMA16(a, w[k0], acc[mt]);
            }
    };
    auto zero4 = [&](f4v* a) {
#pragma unroll
        for (int i = 0; i < 4; ++i) { a[i][0] = 0.f; a[i][1] = 0.f; a[i][2] = 0.f; a[i][3] = 0.f; }
    };
    auto cToC = [&](const f4v* a) {
#pragma unroll
        for (int mt = 0; mt < 4; ++mt)
#pragma unroll
            for (int r = 0; r < 4; ++r)
                sCT[(mt * 16 + lq * 4 + r) * SX_S + wv * 16 + lm] = (_Float16)a[mt][r];
    };
    auto cToT = [&](const f4v* a) {
#pragma unroll
        for (int mt = 0; mt < 4; ++mt) {
            h4v h;
#pragma unroll
            for (int r = 0; r < 4; ++r) h[r] = (_Float16)a[mt][r];
            *(h4v*)(sCT + (wv * 16 + lm) * ST_S + mt * 16 + lq * 4) = h;
        }
    };
    auto copyC = [&](_Float16* dst0) {
        const int r = tid >> 3, c0 = (tid & 7) * 16;
        const _Float16* s = sCT + r * SX_S + c0;
        _Float16* d = dst0 + (t0 + r) * DD + c0;
        *(h8v*)(d)     = *(const h8v*)(s);
        *(h8v*)(d + 8) = *(const h8v*)(s + 8);
    };
    auto copyT = [&](_Float16* dst0) {
        const int dd = tid >> 2, c0 = (tid & 3) * 16;
        const _Float16* s = sCT + dd * ST_S + c0;
        _Float16* d = dst0 + ((long)b * DD + dd) * TSEQ + tin + c0;
        *(h8v*)(d)     = *(const h8v*)(s);
        *(h8v*)(d + 8) = *(const h8v*)(s + 8);
    };

    h8v w[4], w2[4];
    f4v a1[4], a2[4];

    loadW(0, w);
    __syncthreads();                           // B1: sX ready

    // ---------------- Q chain
    loadW(3, w2);
    zero4(a1); gemm(sX, w, a1);                // q
    cToC(a1);
    __syncthreads();                           // B2: sCT = q
    loadW(4, w);
    zero4(a1); gemm(sCT, w2, a1);              // fq1
    loadW(1, w2);
    zero4(a2); gemm(sCT, w, a2);               // fq2
    __syncthreads();                           // B3
#pragma unroll
    for (int mt = 0; mt < 4; ++mt)
#pragma unroll
        for (int r = 0; r < 4; ++r)
            a1[mt][r] = (a1[mt][r] + vb1q) * (a2[mt][r] + vb2q);
    cToC(a1);
    __syncthreads();                           // B4: sCT = qf
    copyC(qf);
    loadW(5, w);
    zero4(a1); gemm(sX, w2, a1);               // k
    __syncthreads();                           // B5
    cToC(a1);
    __syncthreads();                           // B6: sCT = k
    loadW(6, w2);
    zero4(a1); gemm(sCT, w, a1);               // fk1
    loadW(2, w);
    zero4(a2); gemm(sCT, w2, a2);              // fk2
    __syncthreads();                           // B7
#pragma unroll
    for (int mt = 0; mt < 4; ++mt)
#pragma unroll
        for (int r = 0; r < 4; ++r)
            a1[mt][r] = (a1[mt][r] + vb1k) * (a2[mt][r] + vb2k);
    cToT(a1);
    __syncthreads();                           // B8: sCT = kf^T
    copyT(kfT);
    zero4(a1); gemm(sX, w, a1);                // v
    __syncthreads();                           // B9
    cToT(a1);
    __syncthreads();                           // B10: sCT = v^T
    copyT(vT);
}

// ---------------------------------------------------------------------------
// K2 (split-K, no atomics, unchanged): grid (64, NB) = 1024 blocks.
// ---------------------------------------------------------------------------
constexpr int K2_KT = 256;
constexpr int K2_TC = 64;
constexpr int K2_SPLIT = TSEQ / K2_KT;

__global__ __launch_bounds__(256, 4) void k2_kv(const _Float16* __restrict__ kfT,
                                                const _Float16* __restrict__ vT,
                                                float* __restrict__ STf)
{
    __shared__ _Float16 sV[DD * ST_S];
    __shared__ _Float16 sK[DD * ST_S];
    const int tid = threadIdx.x;
    const int wv = tid >> 6, ln = tid & 63, lm = ln & 15, lq = ln >> 4;
    const int b = blockIdx.y;
    const int tbase = blockIdx.x * K2_KT;
    const _Float16* kb = kfT + (long)b * DD * TSEQ;
    const _Float16* vb = vT  + (long)b * DD * TSEQ;
    f4v acc[2][8];
#pragma unroll
    for (int i = 0; i < 2; ++i)
#pragma unroll
        for (int j = 0; j < 8; ++j) { acc[i][j][0]=0.f; acc[i][j][1]=0.f; acc[i][j][2]=0.f; acc[i][j][3]=0.f; }

    for (int tc = 0; tc < K2_KT; tc += K2_TC) {
        const int r = tid >> 1, c0 = (tid & 1) * 32;
        const long g = (long)r * TSEQ + tbase + tc + c0;
#pragma unroll
        for (int i = 0; i < 4; ++i) {
            *(h8v*)(sV + r * ST_S + c0 + i * 8) = *(const h8v*)(vb + g + i * 8);
            *(h8v*)(sK + r * ST_S + c0 + i * 8) = *(const h8v*)(kb + g + i * 8);
        }
        __syncthreads();
#pragma unroll
        for (int k0 = 0; k0 < 2; ++k0) {
            const h8v a0 = *(const h8v*)(sV + ((wv * 2 + 0) * 16 + lm) * ST_S + k0 * 32 + lq * 8);
            const h8v a1 = *(const h8v*)(sV + ((wv * 2 + 1) * 16 + lm) * ST_S + k0 * 32 + lq * 8);
#pragma unroll
            for (int nt = 0; nt < 8; ++nt) {
                const h8v bb = *(const h8v*)(sK + (nt * 16 + lm) * ST_S + k0 * 32 + lq * 8);
                acc[0][nt] = MFMA16(a0, bb, acc[0][nt]);
                acc[1][nt] = MFMA16(a1, bb, acc[1][nt]);
            }
        }
        __syncthreads();
    }
    float* Pb = STf + (long)(b * K2_SPLIT + blockIdx.x) * (DD * DD);
#pragma unroll
    for (int i = 0; i < 2; ++i)
#pragma unroll
        for (int nt = 0; nt < 8; ++nt)
#pragma unroll
            for (int r = 0; r < 4; ++r)
                Pb[((wv * 2 + i) * 16 + lq * 4 + r) * DD + nt * 16 + lm] = acc[i][nt][r];
}

// ---------------------------------------------------------------------------
// K2r: sum the 64 split-K partials per batch -> fp16 S^T.
// ---------------------------------------------------------------------------
__global__ __launch_bounds__(256) void k2r_reduce(const float* __restrict__ STf,
                                                  _Float16* __restrict__ STh)
{
    const int idx = blockIdx.x * 256 + threadIdx.x;
    const int b = idx >> 14, e = idx & (DD * DD - 1);
    const float* p = STf + (long)b * K2_SPLIT * (DD * DD) + e;
    float s0 = 0.f, s1 = 0.f, s2 = 0.f, s3 = 0.f;
#pragma unroll
    for (int j = 0; j < K2_SPLIT; j += 4) {
        s0 += p[(long)(j + 0) * (DD * DD)];
        s1 += p[(long)(j + 1) * (DD * DD)];
        s2 += p[(long)(j + 2) * (DD * DD)];
        s3 += p[(long)(j + 3) * (DD * DD)];
    }
    STh[idx] = (_Float16)((s0 + s1) + (s2 + s3));
}

// ---------------------------------------------------------------------------
// K3 (R8 2x4 wave tiling, validated): 128-t slabs, 512 threads, 8 waves.
// ---------------------------------------------------------------------------
constexpr int K3_TC = 128;

__global__ __launch_bounds__(512, 4) void k3_ostage(const _Float16* __restrict__ qf,
                                                    const _Float16* __restrict__ STh,
                                                    const _Float16* __restrict__ WoH,
                                                    float* __restrict__ pooled)
{
    __shared__ _Float16 sA[DD * SW_S];
    __shared__ _Float16 sB[K3_TC * SX_S];
    __shared__ float sPart[2][DD];
    __shared__ float sRed[8][DD];
    const int tid = threadIdx.x;
    const int wv = tid >> 6, ln = tid & 63, lm = ln & 15, lq = ln >> 4;
    const int eg = wv & 1;
    const int tg = wv >> 1;
    const long t0 = (long)blockIdx.x * K3_TC;
    const int b = (int)(t0 >> 14);

    h8v wo[4];
    {
        const int r = tid >> 2, c0 = (tid & 3) * 32;
        const _Float16* src = WoH + r * DD + c0;
        wo[0] = *(const h8v*)(src);
        wo[1] = *(const h8v*)(src + 8);
        wo[2] = *(const h8v*)(src + 16);
        wo[3] = *(const h8v*)(src + 24);
    }
    {
        const int r = tid >> 2, c0 = (tid & 3) * 32;
        const _Float16* src = STh + (long)b * DD * DD + r * DD + c0;
        _Float16* dst = sA + r * SW_S + c0;
        *(h8v*)(dst)      = *(const h8v*)(src);
        *(h8v*)(dst + 8)  = *(const h8v*)(src + 8);
        *(h8v*)(dst + 16) = *(const h8v*)(src + 16);
        *(h8v*)(dst + 24) = *(const h8v*)(src + 24);
    }
    {
        const int r = tid >> 2, c0 = (tid & 3) * 32;
        const _Float16* src = qf + (t0 + r) * DD + c0;
        _Float16* dst = sB + r * SX_S + c0;
        *(h8v*)(dst)      = *(const h8v*)(src);
        *(h8v*)(dst + 8)  = *(const h8v*)(src + 8);
        *(h8v*)(dst + 16) = *(const h8v*)(src + 16);
        *(h8v*)(dst + 24) = *(const h8v*)(src + 24);
    }
    __syncthreads();                        // B1

    f4v acc[2][4];
#pragma unroll
    for (int i = 0; i < 2; ++i)
#pragma unroll
        for (int j = 0; j < 4; ++j) { acc[i][j][0]=0.f; acc[i][j][1]=0.f; acc[i][j][2]=0.f; acc[i][j][3]=0.f; }
#pragma unroll
    for (int k0 = 0; k0 < 4; ++k0) {
        const h8v bf0 = *(const h8v*)(sB + ((tg * 2 + 0) * 16 + lm) * SX_S + k0 * 32 + lq * 8);
        const h8v bf1 = *(const h8v*)(sB + ((tg * 2 + 1) * 16 + lm) * SX_S + k0 * 32 + lq * 8);
#pragma unroll
        for (int a = 0; a < 4; ++a) {
            const h8v af = *(const h8v*)(sA + ((eg * 4 + a) * 16 + lm) * SW_S + k0 * 32 + lq * 8);
            acc[0][a] = MFMA16(af, bf0, acc[0][a]);
            acc[1][a] = MFMA16(af, bf1, acc[1][a]);
        }
    }
    float ssp[2] = {0.f, 0.f};
#pragma unroll
    for (int bt = 0; bt < 2; ++bt)
#pragma unroll
        for (int a = 0; a < 4; ++a)
#pragma unroll
            for (int r = 0; r < 4; ++r) ssp[bt] += acc[bt][a][r] * acc[bt][a][r];
#pragma unroll
    for (int bt = 0; bt < 2; ++bt) {
        ssp[bt] += __shfl_xor(ssp[bt], 16, 64);
        ssp[bt] += __shfl_xor(ssp[bt], 32, 64);
    }
    if (lq == 0) {
        sPart[eg][tg * 32 + 0 * 16 + lm] = ssp[0];
        sPart[eg][tg * 32 + 1 * 16 + lm] = ssp[1];
    }
    __syncthreads();                        // B2
    float sc[2];
#pragma unroll
    for (int bt = 0; bt < 2; ++bt) {
        const int t = tg * 32 + bt * 16 + lm;
        sc[bt] = rsqrtf((sPart[0][t] + sPart[1][t]) * (1.0f / DD) + EPS);
    }
#pragma unroll
    for (int bt = 0; bt < 2; ++bt)
#pragma unroll
        for (int a = 0; a < 4; ++a) {
            h4v h;
#pragma unroll
            for (int r = 0; r < 4; ++r) h[r] = (_Float16)(acc[bt][a][r] * sc[bt]);
            *(h4v*)(sB + ((tg * 2 + bt) * 16 + lm) * SX_S + (eg * 4 + a) * 16 + lq * 4) = h;
        }
    {
        const int r = tid >> 2, c0 = (tid & 3) * 32;
        _Float16* dst = sA + r * SW_S + c0;
        *(h8v*)(dst)      = wo[0];
        *(h8v*)(dst + 8)  = wo[1];
        *(h8v*)(dst + 16) = wo[2];
        *(h8v*)(dst + 24) = wo[3];
    }
    __syncthreads();                        // B3

#pragma unroll
    for (int i = 0; i < 2; ++i)
#pragma unroll
        for (int j = 0; j < 4; ++j) { acc[i][j][0]=0.f; acc[i][j][1]=0.f; acc[i][j][2]=0.f; acc[i][j][3]=0.f; }
#pragma unroll
    for (int k0 = 0; k0 < 4; ++k0) {
        const h8v bf0 = *(const h8v*)(sB + ((tg * 2 + 0) * 16 + lm) * SX_S + k0 * 32 + lq * 8);
        const h8v bf1 = *(const h8v*)(sB + ((tg * 2 + 1) * 16 + lm) * SX_S + k0 * 32 + lq * 8);
#pragma unroll
        for (int a = 0; a < 4; ++a) {
            const h8v af = *(const h8v*)(sA + ((eg * 4 + a) * 16 + lm) * SW_S + k0 * 32 + lq * 8);
            acc[0][a] = MFMA16(af, bf0, acc[0][a]);
            acc[1][a] = MFMA16(af, bf1, acc[1][a]);
        }
    }
#pragma unroll
    for (int a = 0; a < 4; ++a)
#pragma unroll
        for (int r = 0; r < 4; ++r) {
            float m = fmaxf(acc[0][a][r], acc[1][a][r]);
            m = fmaxf(m, __shfl_xor(m, 1, 64));
            m = fmaxf(m, __shfl_xor(m, 2, 64));
            m = fmaxf(m, __shfl_xor(m, 4, 64));
            m = fmaxf(m, __shfl_xor(m, 8, 64));
            if (lm == 0) sRed[wv][(eg * 4 + a) * 16 + lq * 4 + r] = m;
        }
    __syncthreads();                        // B4
    if (tid < DD) {
        const int egc = tid >> 6;
        float m = sRed[0 * 2 + egc][tid];
#pragma unroll
        for (int g = 1; g < 4; ++g) m = fmaxf(m, sRed[g * 2 + egc][tid]);
        atomicMaxFloat(&pooled[b * DD + tid], m);
    }
}

// ---------------------------------------------------------------------------
// K4: out[b,h] = pooled[b] . Wp[h] + bp[h]
// ---------------------------------------------------------------------------
__global__ __launch_bounds__(HH) void k4_final(const float* __restrict__ pooled,
                                               const float* __restrict__ Wp,
                                               const float* __restrict__ bp,
                                               float* __restrict__ out)
{
    const int b = blockIdx.x;
    const int h = threadIdx.x;
    __shared__ float sp[DD];
    if (h < DD) sp[h] = pooled[b * DD + h];
    __syncthreads();
    float acc = bp[h];
#pragma unroll 8
    for (int d = 0; d < DD; ++d) acc = fmaf(sp[d], Wp[(long)h * DD + d], acc);
    out[b * HH + h] = acc;
}

// ---------------------------------------------------------------------------
extern "C" void kernel_launch(void* const* d_in, const int* in_sizes, int n_in,
                              void* d_out, int out_size, void* d_ws, size_t ws_size,
                              hipStream_t stream)
{
    const float* x      = (const float*)d_in[0];
    const float* Wq     = (const float*)d_in[1];
    const float* Wk     = (const float*)d_in[2];
    const float* Wv     = (const float*)d_in[3];
    const float* fmq_w1 = (const float*)d_in[4];
    const float* fmq_b1 = (const float*)d_in[5];
    const float* fmq_w2 = (const float*)d_in[6];
    const float* fmq_b2 = (const float*)d_in[7];
    const float* fmk_w1 = (const float*)d_in[8];
    const float* fmk_b1 = (const float*)d_in[9];
    const float* fmk_w2 = (const float*)d_in[10];
    const float* fmk_b2 = (const float*)d_in[11];
    const float* rms_w  = (const float*)d_in[12];
    const float* Wo     = (const float*)d_in[13];
    const float* Wp     = (const float*)d_in[14];
    const float* bp     = (const float*)d_in[15];
    float* out = (float*)d_out;

    const long nTD = (long)NB * TSEQ * DD;
    _Float16* qf  = (_Float16*)d_ws;
    _Float16* kfT = qf + nTD;
    _Float16* vT  = kfT + nTD;
    _Float16* Wh  = vT + nTD;
    float* STf    = (float*)(Wh + 8 * DD * DD);
    _Float16* STh = (_Float16*)(STf + (long)NB * K2_SPLIT * DD * DD);
    float* pooled = (float*)(STh + NB * DD * DD);

    k0_prep<<<512, 256, 0, stream>>>(Wq, Wk, Wv, fmq_w1, fmq_w2, fmk_w1, fmk_w2,
                                     Wo, rms_w, Wh, pooled);
    k1_qkvfm<<<(NB * TSEQ) / 64, 512, 0, stream>>>(
        x, Wh, fmq_b1, fmq_b2, fmk_b1, fmk_b2, qf, kfT, vT);
    k2_kv<<<dim3(K2_SPLIT, NB), 256, 0, stream>>>(kfT, vT, STf);
    k2r_reduce<<<(NB * DD * DD) / 256, 256, 0, stream>>>(STf, STh);
    k3_ostage<<<(NB * TSEQ) / K3_TC, 512, 0, stream>>>(qf, STh, Wh + 7 * DD * DD, pooled);
    k4_final<<<NB, HH, 0, stream>>>(pooled, Wp, bp, out);
}

// Round 11
// 401.894 us; speedup vs baseline: 1.3493x; 1.1446x over previous
//
#include <hip/hip_runtime.h>
#include <math.h>

#define NB   16
#define TSEQ 16384
#define DD   128
#define HH   256
constexpr float EPS = 1e-5f;

typedef _Float16 h8v __attribute__((ext_vector_type(8)));
typedef _Float16 h4v __attribute__((ext_vector_type(4)));
typedef float    f4v __attribute__((ext_vector_type(4)));

#define MFMA16(a, b, c) __builtin_amdgcn_mfma_f32_16x16x32_f16(a, b, c, 0, 0, 0)

constexpr int SX_S = 136;   // 272B rows: 2-way bank alias on b128 (free)
constexpr int SW_S = 136;
constexpr int ST_S = 72;

__device__ __forceinline__ void atomicMaxFloat(float* addr, float val) {
    if (val >= 0.0f) atomicMax((int*)addr, __float_as_int(val));
    else             atomicMin((unsigned int*)addr, __float_as_uint(val));
}

// ---------------------------------------------------------------------------
// K0: weights fp32->fp16 (rms_w folded into Wo), init pooled.
// ---------------------------------------------------------------------------
__global__ __launch_bounds__(256) void k0_prep(
    const float* __restrict__ Wq, const float* __restrict__ Wk,
    const float* __restrict__ Wv, const float* __restrict__ fq1,
    const float* __restrict__ fq2, const float* __restrict__ fk1,
    const float* __restrict__ fk2, const float* __restrict__ Wo,
    const float* __restrict__ rmsw,
    _Float16* __restrict__ Wh, float* __restrict__ pooled)
{
    const int i = blockIdx.x * 256 + threadIdx.x;
    if (i < 8 * DD * DD) {
        const int mat = i >> 14;
        const int e   = i & (DD * DD - 1);
        const float* srcs[8] = {Wq, Wk, Wv, fq1, fq2, fk1, fk2, Wo};
        float v = srcs[mat][e];
        if (mat == 7) v *= rmsw[e & (DD - 1)];
        Wh[i] = (_Float16)v;
    }
    if (i < NB * DD)      pooled[i] = -INFINITY;
}

// ---------------------------------------------------------------------------
// K1 (R11: 128-t tile, same 10-barrier chain amortized over 2x work).
// 512 threads, 8 waves; wave wv owns n-tile wv across 8 m-tiles.
// Weight B-frags in registers (w[4]/w2[4]); (512,4) cap=128 VGPR, body ~110.
// LDS: sX 34816 + sCT 34816 = 69632 B -> 2 blocks/CU.
// Coverage: all block-wide copies are 512 thr x 32 elems = 16384 = 128x128.
// ---------------------------------------------------------------------------
constexpr int K1_TM = 128;

__global__ __launch_bounds__(512, 4) void k1_qkvfm(
    const float* __restrict__ x, const _Float16* __restrict__ Wh,
    const float* __restrict__ bq1, const float* __restrict__ bq2,
    const float* __restrict__ bk1, const float* __restrict__ bk2,
    _Float16* __restrict__ qf, _Float16* __restrict__ kfT,
    _Float16* __restrict__ vT)
{
    __shared__ _Float16 sX[K1_TM * SX_S];    // x tile [t][d]
    __shared__ _Float16 sCT[K1_TM * SX_S];   // union: chain [t][d] / transpose [d][t]

    const int tid = threadIdx.x;
    const int wv = tid >> 6;                 // 0..7 -> n-tile
    const int ln = tid & 63, lm = ln & 15, lq = ln >> 4;
    const long t0 = (long)blockIdx.x * K1_TM;
    const int b = (int)(t0 >> 14), tin = (int)(t0 & (TSEQ - 1));

    const float vb1q = bq1[wv * 16 + lm], vb2q = bq2[wv * 16 + lm];
    const float vb1k = bk1[wv * 16 + lm], vb2k = bk2[wv * 16 + lm];

    {   // stage x [128][128] fp32->fp16: r=tid>>2 (0..127), c0=(tid&3)*32
        const int r = tid >> 2, c0 = (tid & 3) * 32;
        const float* src = x + (t0 + r) * DD + c0;
        _Float16* dst = sX + r * SX_S + c0;
#pragma unroll
        for (int i = 0; i < 8; ++i) {
            const float4 v = *(const float4*)(src + i * 4);
            h4v h; h[0] = (_Float16)v.x; h[1] = (_Float16)v.y;
                   h[2] = (_Float16)v.z; h[3] = (_Float16)v.w;
            *(h4v*)(dst + i * 4) = h;
        }
    }

    auto loadW = [&](int mat, h8v* w) {
        const _Float16* p = Wh + mat * DD * DD + (wv * 16 + lm) * DD + lq * 8;
#pragma unroll
        for (int k0 = 0; k0 < 4; ++k0) w[k0] = *(const h8v*)(p + k0 * 32);
    };
    auto gemm = [&](const _Float16* sA, const h8v* w, f4v* acc) {
#pragma unroll
        for (int k0 = 0; k0 < 4; ++k0)
#pragma unroll
            for (int mt = 0; mt < 8; ++mt) {
                const h8v a = *(const h8v*)(sA + (mt * 16 + lm) * SX_S + k0 * 32 + lq * 8);
                acc[mt] = MFMA16(a, w[k0], acc[mt]);
            }
    };
    auto zero8 = [&](f4v* a) {
#pragma unroll
        for (int i = 0; i < 8; ++i) { a[i][0] = 0.f; a[i][1] = 0.f; a[i][2] = 0.f; a[i][3] = 0.f; }
    };
    auto cToC = [&](const f4v* a) {          // C frags -> sCT [t][d]
#pragma unroll
        for (int mt = 0; mt < 8; ++mt)
#pragma unroll
            for (int r = 0; r < 4; ++r)
                sCT[(mt * 16 + lq * 4 + r) * SX_S + wv * 16 + lm] = (_Float16)a[mt][r];
    };
    auto cToT = [&](const f4v* a) {          // C frags -> sCT [d][t] (h4v: 4 consec t)
#pragma unroll
        for (int mt = 0; mt < 8; ++mt) {
            h4v h;
#pragma unroll
            for (int r = 0; r < 4; ++r) h[r] = (_Float16)a[mt][r];
            *(h4v*)(sCT + (wv * 16 + lm) * SX_S + mt * 16 + lq * 4) = h;
        }
    };
    auto copyC = [&](_Float16* dst0) {       // [128][128] -> global [t][d]
        const int r = tid >> 2, c0 = (tid & 3) * 32;
        const _Float16* s = sCT + r * SX_S + c0;
        _Float16* d = dst0 + (t0 + r) * DD + c0;
        *(h8v*)(d)      = *(const h8v*)(s);
        *(h8v*)(d + 8)  = *(const h8v*)(s + 8);
        *(h8v*)(d + 16) = *(const h8v*)(s + 16);
        *(h8v*)(d + 24) = *(const h8v*)(s + 24);
    };
    auto copyT = [&](_Float16* dst0) {       // [128 d][128 t] -> global [d][t]
        const int dd = tid >> 2, c0 = (tid & 3) * 32;
        const _Float16* s = sCT + dd * SX_S + c0;
        _Float16* d = dst0 + ((long)b * DD + dd) * TSEQ + tin + c0;
        *(h8v*)(d)      = *(const h8v*)(s);
        *(h8v*)(d + 8)  = *(const h8v*)(s + 8);
        *(h8v*)(d + 16) = *(const h8v*)(s + 16);
        *(h8v*)(d + 24) = *(const h8v*)(s + 24);
    };

    h8v w[4], w2[4];
    f4v a1[8], a2[8];

    loadW(0, w);
    __syncthreads();                           // B1: sX ready

    // ---------------- Q chain
    loadW(3, w2);
    zero8(a1); gemm(sX, w, a1);                // q
    cToC(a1);
    __syncthreads();                           // B2: sCT = q
    loadW(4, w);
    zero8(a1); gemm(sCT, w2, a1);              // fq1
    loadW(1, w2);
    zero8(a2); gemm(sCT, w, a2);               // fq2
    __syncthreads();                           // B3: all q reads done
#pragma unroll
    for (int mt = 0; mt < 8; ++mt)
#pragma unroll
        for (int r = 0; r < 4; ++r)
            a1[mt][r] = (a1[mt][r] + vb1q) * (a2[mt][r] + vb2q);
    cToC(a1);
    __syncthreads();                           // B4: sCT = qf
    copyC(qf);
    loadW(5, w);
    zero8(a1); gemm(sX, w2, a1);               // k (reads sX only)
    __syncthreads();                           // B5: copyC reads done
    cToC(a1);
    __syncthreads();                           // B6: sCT = k
    loadW(6, w2);
    zero8(a1); gemm(sCT, w, a1);               // fk1
    loadW(2, w);
    zero8(a2); gemm(sCT, w2, a2);              // fk2
    __syncthreads();                           // B7: all k reads done
#pragma unroll
    for (int mt = 0; mt < 8; ++mt)
#pragma unroll
        for (int r = 0; r < 4; ++r)
            a1[mt][r] = (a1[mt][r] + vb1k) * (a2[mt][r] + vb2k);
    cToT(a1);
    __syncthreads();                           // B8: sCT = kf^T
    copyT(kfT);
    zero8(a1); gemm(sX, w, a1);                // v
    __syncthreads();                           // B9: copyT reads done
    cToT(a1);
    __syncthreads();                           // B10: sCT = v^T
    copyT(vT);
}

// ---------------------------------------------------------------------------
// K2 (split-K, no atomics; R11: split 32 -> half the partial traffic).
// grid (32, NB) = 512 blocks; each reduces 512 t and stores a [128][128]
// fp32 partial contiguously.
// ---------------------------------------------------------------------------
constexpr int K2_KT = 512;
constexpr int K2_TC = 64;
constexpr int K2_SPLIT = TSEQ / K2_KT;        // 32

__global__ __launch_bounds__(256, 4) void k2_kv(const _Float16* __restrict__ kfT,
                                                const _Float16* __restrict__ vT,
                                                float* __restrict__ STf)
{
    __shared__ _Float16 sV[DD * ST_S];
    __shared__ _Float16 sK[DD * ST_S];
    const int tid = threadIdx.x;
    const int wv = tid >> 6, ln = tid & 63, lm = ln & 15, lq = ln >> 4;
    const int b = blockIdx.y;
    const int tbase = blockIdx.x * K2_KT;
    const _Float16* kb = kfT + (long)b * DD * TSEQ;
    const _Float16* vb = vT  + (long)b * DD * TSEQ;
    f4v acc[2][8];
#pragma unroll
    for (int i = 0; i < 2; ++i)
#pragma unroll
        for (int j = 0; j < 8; ++j) { acc[i][j][0]=0.f; acc[i][j][1]=0.f; acc[i][j][2]=0.f; acc[i][j][3]=0.f; }

    for (int tc = 0; tc < K2_KT; tc += K2_TC) {
        const int r = tid >> 1, c0 = (tid & 1) * 32;
        const long g = (long)r * TSEQ + tbase + tc + c0;
#pragma unroll
        for (int i = 0; i < 4; ++i) {
            *(h8v*)(sV + r * ST_S + c0 + i * 8) = *(const h8v*)(vb + g + i * 8);
            *(h8v*)(sK + r * ST_S + c0 + i * 8) = *(const h8v*)(kb + g + i * 8);
        }
        __syncthreads();
#pragma unroll
        for (int k0 = 0; k0 < 2; ++k0) {
            const h8v a0 = *(const h8v*)(sV + ((wv * 2 + 0) * 16 + lm) * ST_S + k0 * 32 + lq * 8);
            const h8v a1 = *(const h8v*)(sV + ((wv * 2 + 1) * 16 + lm) * ST_S + k0 * 32 + lq * 8);
#pragma unroll
            for (int nt = 0; nt < 8; ++nt) {
                const h8v bb = *(const h8v*)(sK + (nt * 16 + lm) * ST_S + k0 * 32 + lq * 8);
                acc[0][nt] = MFMA16(a0, bb, acc[0][nt]);
                acc[1][nt] = MFMA16(a1, bb, acc[1][nt]);
            }
        }
        __syncthreads();
    }
    float* Pb = STf + (long)(b * K2_SPLIT + blockIdx.x) * (DD * DD);
#pragma unroll
    for (int i = 0; i < 2; ++i)
#pragma unroll
        for (int nt = 0; nt < 8; ++nt)
#pragma unroll
            for (int r = 0; r < 4; ++r)
                Pb[((wv * 2 + i) * 16 + lq * 4 + r) * DD + nt * 16 + lm] = acc[i][nt][r];
}

// ---------------------------------------------------------------------------
// K2r: sum the 32 split-K partials per batch -> fp16 S^T.
// ---------------------------------------------------------------------------
__global__ __launch_bounds__(256) void k2r_reduce(const float* __restrict__ STf,
                                                  _Float16* __restrict__ STh)
{
    const int idx = blockIdx.x * 256 + threadIdx.x;
    const int b = idx >> 14, e = idx & (DD * DD - 1);
    const float* p = STf + (long)b * K2_SPLIT * (DD * DD) + e;
    float s0 = 0.f, s1 = 0.f, s2 = 0.f, s3 = 0.f;
#pragma unroll
    for (int j = 0; j < K2_SPLIT; j += 4) {
        s0 += p[(long)(j + 0) * (DD * DD)];
        s1 += p[(long)(j + 1) * (DD * DD)];
        s2 += p[(long)(j + 2) * (DD * DD)];
        s3 += p[(long)(j + 3) * (DD * DD)];
    }
    STh[idx] = (_Float16)((s0 + s1) + (s2 + s3));
}

// ---------------------------------------------------------------------------
// K3 (R8 2x4 wave tiling, validated; unchanged from R10).
// ---------------------------------------------------------------------------
constexpr int K3_TC = 128;

__global__ __launch_bounds__(512, 4) void k3_ostage(const _Float16* __restrict__ qf,
                                                    const _Float16* __restrict__ STh,
                                                    const _Float16* __restrict__ WoH,
                                                    float* __restrict__ pooled)
{
    __shared__ _Float16 sA[DD * SW_S];
    __shared__ _Float16 sB[K3_TC * SX_S];
    __shared__ float sPart[2][DD];
    __shared__ float sRed[8][DD];
    const int tid = threadIdx.x;
    const int wv = tid >> 6, ln = tid & 63, lm = ln & 15, lq = ln >> 4;
    const int eg = wv & 1;
    const int tg = wv >> 1;
    const long t0 = (long)blockIdx.x * K3_TC;
    const int b = (int)(t0 >> 14);

    h8v wo[4];
    {
        const int r = tid >> 2, c0 = (tid & 3) * 32;
        const _Float16* src = WoH + r * DD + c0;
        wo[0] = *(const h8v*)(src);
        wo[1] = *(const h8v*)(src + 8);
        wo[2] = *(const h8v*)(src + 16);
        wo[3] = *(const h8v*)(src + 24);
    }
    {
        const int r = tid >> 2, c0 = (tid & 3) * 32;
        const _Float16* src = STh + (long)b * DD * DD + r * DD + c0;
        _Float16* dst = sA + r * SW_S + c0;
        *(h8v*)(dst)      = *(const h8v*)(src);
        *(h8v*)(dst + 8)  = *(const h8v*)(src + 8);
        *(h8v*)(dst + 16) = *(const h8v*)(src + 16);
        *(h8v*)(dst + 24) = *(const h8v*)(src + 24);
    }
    {
        const int r = tid >> 2, c0 = (tid & 3) * 32;
        const _Float16* src = qf + (t0 + r) * DD + c0;
        _Float16* dst = sB + r * SX_S + c0;
        *(h8v*)(dst)      = *(const h8v*)(src);
        *(h8v*)(dst + 8)  = *(const h8v*)(src + 8);
        *(h8v*)(dst + 16) = *(const h8v*)(src + 16);
        *(h8v*)(dst + 24) = *(const h8v*)(src + 24);
    }
    __syncthreads();                        // B1

    f4v acc[2][4];
#pragma unroll
    for (int i = 0; i < 2; ++i)
#pragma unroll
        for (int j = 0; j < 4; ++j) { acc[i][j][0]=0.f; acc[i][j][1]=0.f; acc[i][j][2]=0.f; acc[i][j][3]=0.f; }
#pragma unroll
    for (int k0 = 0; k0 < 4; ++k0) {
        const h8v bf0 = *(const h8v*)(sB + ((tg * 2 + 0) * 16 + lm) * SX_S + k0 * 32 + lq * 8);
        const h8v bf1 = *(const h8v*)(sB + ((tg * 2 + 1) * 16 + lm) * SX_S + k0 * 32 + lq * 8);
#pragma unroll
        for (int a = 0; a < 4; ++a) {
            const h8v af = *(const h8v*)(sA + ((eg * 4 + a) * 16 + lm) * SW_S + k0 * 32 + lq * 8);
            acc[0][a] = MFMA16(af, bf0, acc[0][a]);
            acc[1][a] = MFMA16(af, bf1, acc[1][a]);
        }
    }
    float ssp[2] = {0.f, 0.f};
#pragma unroll
    for (int bt = 0; bt < 2; ++bt)
#pragma unroll
        for (int a = 0; a < 4; ++a)
#pragma unroll
            for (int r = 0; r < 4; ++r) ssp[bt] += acc[bt][a][r] * acc[bt][a][r];
#pragma unroll
    for (int bt = 0; bt < 2; ++bt) {
        ssp[bt] += __shfl_xor(ssp[bt], 16, 64);
        ssp[bt] += __shfl_xor(ssp[bt], 32, 64);
    }
    if (lq == 0) {
        sPart[eg][tg * 32 + 0 * 16 + lm] = ssp[0];
        sPart[eg][tg * 32 + 1 * 16 + lm] = ssp[1];
    }
    __syncthreads();                        // B2
    float sc[2];
#pragma unroll
    for (int bt = 0; bt < 2; ++bt) {
        const int t = tg * 32 + bt * 16 + lm;
        sc[bt] = rsqrtf((sPart[0][t] + sPart[1][t]) * (1.0f / DD) + EPS);
    }
#pragma unroll
    for (int bt = 0; bt < 2; ++bt)
#pragma unroll
        for (int a = 0; a < 4; ++a) {
            h4v h;
#pragma unroll
            for (int r = 0; r < 4; ++r) h[r] = (_Float16)(acc[bt][a][r] * sc[bt]);
            *(h4v*)(sB + ((tg * 2 + bt) * 16 + lm) * SX_S + (eg * 4 + a) * 16 + lq * 4) = h;
        }
    {
        const int r = tid >> 2, c0 = (tid & 3) * 32;
        _Float16* dst = sA + r * SW_S + c0;
        *(h8v*)(dst)      = wo[0];
        *(h8v*)(dst + 8)  = wo[1];
        *(h8v*)(dst + 16) = wo[2];
        *(h8v*)(dst + 24) = wo[3];
    }
    __syncthreads();                        // B3

#pragma unroll
    for (int i = 0; i < 2; ++i)
#pragma unroll
        for (int j = 0; j < 4; ++j) { acc[i][j][0]=0.f; acc[i][j][1]=0.f; acc[i][j][2]=0.f; acc[i][j][3]=0.f; }
#pragma unroll
    for (int k0 = 0; k0 < 4; ++k0) {
        const h8v bf0 = *(const h8v*)(sB + ((tg * 2 + 0) * 16 + lm) * SX_S + k0 * 32 + lq * 8);
        const h8v bf1 = *(const h8v*)(sB + ((tg * 2 + 1) * 16 + lm) * SX_S + k0 * 32 + lq * 8);
#pragma unroll
        for (int a = 0; a < 4; ++a) {
            const h8v af = *(const h8v*)(sA + ((eg * 4 + a) * 16 + lm) * SW_S + k0 * 32 + lq * 8);
            acc[0][a] = MFMA16(af, bf0, acc[0][a]);
            acc[1][a] = MFMA16(af, bf1, acc[1][a]);
        }
    }
#pragma unroll
    for (int a = 0; a < 4; ++a)
#pragma unroll
        for (int r = 0; r < 4; ++r) {
            float m = fmaxf(acc[0][a][r], acc[1][a][r]);
            m = fmaxf(m, __shfl_xor(m, 1, 64));
            m = fmaxf(m, __shfl_xor(m, 2, 64));
            m = fmaxf(m, __shfl_xor(m, 4, 64));
            m = fmaxf(m, __shfl_xor(m, 8, 64));
            if (lm == 0) sRed[wv][(eg * 4 + a) * 16 + lq * 4 + r] = m;
        }
    __syncthreads();                        // B4
    if (tid < DD) {
        const int egc = tid >> 6;
        float m = sRed[0 * 2 + egc][tid];
#pragma unroll
        for (int g = 1; g < 4; ++g) m = fmaxf(m, sRed[g * 2 + egc][tid]);
        atomicMaxFloat(&pooled[b * DD + tid], m);
    }
}

// ---------------------------------------------------------------------------
// K4: out[b,h] = pooled[b] . Wp[h] + bp[h]
// ---------------------------------------------------------------------------
__global__ __launch_bounds__(HH) void k4_final(const float* __restrict__ pooled,
                                               const float* __restrict__ Wp,
                                               const float* __restrict__ bp,
                                               float* __restrict__ out)
{
    const int b = blockIdx.x;
    const int h = threadIdx.x;
    __shared__ float sp[DD];
    if (h < DD) sp[h] = pooled[b * DD + h];
    __syncthreads();
    float acc = bp[h];
#pragma unroll 8
    for (int d = 0; d < DD; ++d) acc = fmaf(sp[d], Wp[(long)h * DD + d], acc);
    out[b * HH + h] = acc;
}

// ---------------------------------------------------------------------------
extern "C" void kernel_launch(void* const* d_in, const int* in_sizes, int n_in,
                              void* d_out, int out_size, void* d_ws, size_t ws_size,
                              hipStream_t stream)
{
    const float* x      = (const float*)d_in[0];
    const float* Wq     = (const float*)d_in[1];
    const float* Wk     = (const float*)d_in[2];
    const float* Wv     = (const float*)d_in[3];
    const float* fmq_w1 = (const float*)d_in[4];
    const float* fmq_b1 = (const float*)d_in[5];
    const float* fmq_w2 = (const float*)d_in[6];
    const float* fmq_b2 = (const float*)d_in[7];
    const float* fmk_w1 = (const float*)d_in[8];
    const float* fmk_b1 = (const float*)d_in[9];
    const float* fmk_w2 = (const float*)d_in[10];
    const float* fmk_b2 = (const float*)d_in[11];
    const float* rms_w  = (const float*)d_in[12];
    const float* Wo     = (const float*)d_in[13];
    const float* Wp     = (const float*)d_in[14];
    const float* bp     = (const float*)d_in[15];
    float* out = (float*)d_out;

    const long nTD = (long)NB * TSEQ * DD;
    _Float16* qf  = (_Float16*)d_ws;
    _Float16* kfT = qf + nTD;
    _Float16* vT  = kfT + nTD;
    _Float16* Wh  = vT + nTD;
    float* STf    = (float*)(Wh + 8 * DD * DD);
    _Float16* STh = (_Float16*)(STf + (long)NB * K2_SPLIT * DD * DD);
    float* pooled = (float*)(STh + NB * DD * DD);

    k0_prep<<<512, 256, 0, stream>>>(Wq, Wk, Wv, fmq_w1, fmq_w2, fmk_w1, fmk_w2,
                                     Wo, rms_w, Wh, pooled);
    k1_qkvfm<<<(NB * TSEQ) / K1_TM, 512, 0, stream>>>(
        x, Wh, fmq_b1, fmq_b2, fmk_b1, fmk_b2, qf, kfT, vT);
    k2_kv<<<dim3(K2_SPLIT, NB), 256, 0, stream>>>(kfT, vT, STf);
    k2r_reduce<<<(NB * DD * DD) / 256, 256, 0, stream>>>(STf, STh);
    k3_ostage<<<(NB * TSEQ) / K3_TC, 512, 0, stream>>>(qf, STh, Wh + 7 * DD * DD, pooled);
    k4_final<<<NB, HH, 0, stream>>>(pooled, Wp, bp, out);
}